// Round 4
// baseline (300.563 us; speedup 1.0000x reference)
//
#include <hip/hip_runtime.h>

#define NUM_EMB 1024
#define EMB_DIM 256
#define NPIX    32768      // 32 * 32 * 32
#define HW      1024       // 32*32 spatial per batch
#define ZQ_ELEMS 8388608   // 32*256*32*32

// ws layout (bytes):
//   [0..8)                  double loss_accum
//   [8..8+4096)             float  tnorm[1024]
//   [8192..8192+131072)     float  snorm[32768]
//   [139264..139264+262144) u64   keys[32768]  (argmin: (d_bits<<32)|idx)
#define WS_TNORM 8
#define WS_SNORM 8192
#define WS_KEYS  139264

typedef unsigned long long u64;
typedef unsigned int u32;
typedef unsigned short u16;

typedef __bf16 bf16x8 __attribute__((ext_vector_type(8)));
typedef float f32x4 __attribute__((ext_vector_type(4)));

// ---- numpy pairwise_sum replica over 128 squared terms, stride between terms ----
__device__ __forceinline__ float pw128_sq(const float* x, int stride) {
  float r[8];
#pragma unroll
  for (int j = 0; j < 8; ++j) {
    float v = x[(size_t)j * stride];
    r[j] = __fmul_rn(v, v);
  }
  for (int i = 8; i < 128; i += 8) {
#pragma unroll
    for (int j = 0; j < 8; ++j) {
      float v = x[(size_t)(i + j) * stride];
      r[j] = __fadd_rn(r[j], __fmul_rn(v, v));
    }
  }
  float s01 = __fadd_rn(r[0], r[1]);
  float s23 = __fadd_rn(r[2], r[3]);
  float s45 = __fadd_rn(r[4], r[5]);
  float s67 = __fadd_rn(r[6], r[7]);
  return __fadd_rn(__fadd_rn(s01, s23), __fadd_rn(s45, s67));
}

// 3-way bf16 split: x = hf + mf + lf + eps, eps ~ 2^-26 |x|. Sterbenz-exact residuals.
__device__ __forceinline__ void split3(float x, u16& h, u16& m, u16& l) {
  u32 u = __float_as_uint(x);
  u16 hb = (u16)((u + 0x7fffu + ((u >> 16) & 1u)) >> 16);
  float hf = __uint_as_float((u32)hb << 16);
  float r1 = x - hf;                       // exact
  u32 u1 = __float_as_uint(r1);
  u16 mb = (u16)((u1 + 0x7fffu + ((u1 >> 16) & 1u)) >> 16);
  float mf = __uint_as_float((u32)mb << 16);
  float r2 = r1 - mf;                      // exact
  u32 u2 = __float_as_uint(r2);
  u16 lb = (u16)((u2 + 0x7fffu + ((u2 >> 16) & 1u)) >> 16);
  h = hb; m = mb; l = lb;
}

__device__ __forceinline__ u64 shfl_xor_u64(u64 v, int msk) {
  const u32 lo = __shfl_xor((u32)v, msk, 64);
  const u32 hi = __shfl_xor((u32)(v >> 32), msk, 64);
  return ((u64)hi << 32) | lo;
}

// ---- prep: keys=~0, loss=0, snorm (gid<NPIX), tnorm (gid in [NPIX, NPIX+1024)) ----
__global__ __launch_bounds__(256) void vq_prep_kernel(
    const float* __restrict__ z, const float* __restrict__ emb,
    float* __restrict__ tnorm, float* __restrict__ snorm,
    unsigned long long* __restrict__ keys, double* __restrict__ loss_accum) {
  const int gid = blockIdx.x * 256 + threadIdx.x;
  if (gid == 0) *loss_accum = 0.0;
  if (gid < NPIX) {
    keys[gid] = ~0ull;
    const int b = gid >> 10, hw = gid & 1023;
    const float* base = z + (size_t)b * (EMB_DIM * HW) + hw;
    snorm[gid] = __fadd_rn(pw128_sq(base, HW), pw128_sq(base + (size_t)128 * HW, HW));
  } else {
    const int k = gid - NPIX;
    if (k < NUM_EMB) {
      const float* row = emb + (size_t)k * EMB_DIM;
      tnorm[k] = __fadd_rn(pw128_sq(row, 1), pw128_sq(row + 128, 1));
    }
  }
}

// ---- main: 128 px x 128 codes per block, bf16 3-split x 6-product MFMA GEMM ----
// logical bid: pt = bid>>3 (256 pixel tiles), nt = bid&7 (8 code tiles)
// XCD swizzle: hw bid h -> logical (h&7)*256 + (h>>3)
__global__ __launch_bounds__(256, 2) void vq_main_kernel(
    const float* __restrict__ z, const float* __restrict__ emb,
    const float* __restrict__ tnorm, const float* __restrict__ snorm,
    unsigned long long* __restrict__ keys) {
  // [plane][row][k], rows padded to 40 u16 = 80B (conflict-free b128 frag reads)
  __shared__ __align__(16) u16 zs[3][128][40];   // 30720 B
  __shared__ __align__(16) u16 es[3][128][40];   // 30720 B

  const int t   = threadIdx.x;
  const int hb  = blockIdx.x;
  const int bid = (hb & 7) * 256 + (hb >> 3);
  const int pt  = bid >> 3;
  const int ntb = bid & 7;
  const int m0  = pt * 128;
  const int n0  = ntb * 128;
  const int b   = m0 >> 10;
  const int hw0 = m0 & 1023;
  const float* zbase = z + (size_t)b * (EMB_DIM * HW) + hw0;

  const int l   = t & 63;
  const int wid = t >> 6;
  const int wpx0 = (wid >> 1) * 64;   // wave pixel base within tile
  const int wcb  = (wid & 1) * 64;    // wave code base within tile

  // staging assignment
  const int zpx4  = (t & 31) * 4;     // pixel quad
  const int zk    = t >> 5;           // k row 0..7 (stride 8)
  const int ecode = t >> 1;           // code 0..127
  const int ek0   = (t & 1) * 16;     // k half base
  const float* erow = emb + (size_t)(n0 + ecode) * EMB_DIM + ek0;

  float4 gz[4], ge[4];
#pragma unroll
  for (int r = 0; r < 4; ++r)
    gz[r] = *(const float4*)(zbase + (size_t)(zk + r * 8) * HW + zpx4);
#pragma unroll
  for (int r = 0; r < 4; ++r)
    ge[r] = *(const float4*)(erow + r * 4);

  f32x4 acc[4][4];
#pragma unroll
  for (int i = 0; i < 4; ++i)
#pragma unroll
    for (int j = 0; j < 4; ++j) {
      f32x4 zv = {0.0f, 0.0f, 0.0f, 0.0f};
      acc[i][j] = zv;
    }

  for (int kt = 0; kt < 8; ++kt) {
    // ---- convert + LDS write (z: transpose scatter b16; e: contiguous b64) ----
#pragma unroll
    for (int r = 0; r < 4; ++r) {
      const int kr = zk + r * 8;
      const float xv[4] = {gz[r].x, gz[r].y, gz[r].z, gz[r].w};
#pragma unroll
      for (int c = 0; c < 4; ++c) {
        u16 h, m, lo;
        split3(xv[c], h, m, lo);
        zs[0][zpx4 + c][kr] = h;
        zs[1][zpx4 + c][kr] = m;
        zs[2][zpx4 + c][kr] = lo;
      }
    }
#pragma unroll
    for (int r = 0; r < 4; ++r) {
      const float xv[4] = {ge[r].x, ge[r].y, ge[r].z, ge[r].w};
      u16 h[4], m[4], lo[4];
#pragma unroll
      for (int c = 0; c < 4; ++c) split3(xv[c], h[c], m[c], lo[c]);
      *(ushort4*)&es[0][ecode][ek0 + r * 4] = make_ushort4(h[0], h[1], h[2], h[3]);
      *(ushort4*)&es[1][ecode][ek0 + r * 4] = make_ushort4(m[0], m[1], m[2], m[3]);
      *(ushort4*)&es[2][ecode][ek0 + r * 4] = make_ushort4(lo[0], lo[1], lo[2], lo[3]);
    }
    // ---- issue next tile's globals (latency hides under MFMA) ----
    if (kt < 7) {
      const int kb = (kt + 1) * 32;
#pragma unroll
      for (int r = 0; r < 4; ++r)
        gz[r] = *(const float4*)(zbase + (size_t)(kb + zk + r * 8) * HW + zpx4);
#pragma unroll
      for (int r = 0; r < 4; ++r)
        ge[r] = *(const float4*)(erow + kb + r * 4);
    }
    __syncthreads();

    // ---- fragment loads: lane m/n = l&15, k-octet = l>>4 ----
    const int frow = l & 15;
    const int kg8  = (l >> 4) * 8;
    bf16x8 af[3][4], bf[3][4];
#pragma unroll
    for (int mt = 0; mt < 4; ++mt)
#pragma unroll
      for (int p = 0; p < 3; ++p)
        af[p][mt] = *(const bf16x8*)&zs[p][wpx0 + mt * 16 + frow][kg8];
#pragma unroll
    for (int nn = 0; nn < 4; ++nn)
#pragma unroll
      for (int p = 0; p < 3; ++p)
        bf[p][nn] = *(const bf16x8*)&es[p][wcb + nn * 16 + frow][kg8];

    // ---- 6 split-product planes: hh, hm, mh, mm, hl, lh ----
#define MMPAIR(PA, PB)                                                        \
    _Pragma("unroll")                                                         \
    for (int mt = 0; mt < 4; ++mt) {                                          \
      _Pragma("unroll")                                                       \
      for (int nn = 0; nn < 4; ++nn)                                          \
        acc[mt][nn] = __builtin_amdgcn_mfma_f32_16x16x32_bf16(                \
            af[PA][mt], bf[PB][nn], acc[mt][nn], 0, 0, 0);                    \
    }
    MMPAIR(0, 0)
    MMPAIR(0, 1)
    MMPAIR(1, 0)
    MMPAIR(1, 1)
    MMPAIR(0, 2)
    MMPAIR(2, 0)
#undef MMPAIR
    __syncthreads();
  }

  // ---- epilogue: d = fl(fl(s+t) - 2m); argmin via u64 keys ----
  // C layout (verified): col = l&15 (code), row = (l>>4)*4 + reg (pixel)
  float sv[4][4], tv[4];
#pragma unroll
  for (int mt = 0; mt < 4; ++mt)
#pragma unroll
    for (int r = 0; r < 4; ++r)
      sv[mt][r] = snorm[m0 + wpx0 + mt * 16 + (l >> 4) * 4 + r];
#pragma unroll
  for (int nn = 0; nn < 4; ++nn)
    tv[nn] = tnorm[n0 + wcb + nn * 16 + (l & 15)];

  u64 bk[4][4];
#pragma unroll
  for (int mt = 0; mt < 4; ++mt)
#pragma unroll
    for (int r = 0; r < 4; ++r) {
      u64 best = ~0ull;
#pragma unroll
      for (int nn = 0; nn < 4; ++nn) {
        const float d =
            __fsub_rn(__fadd_rn(sv[mt][r], tv[nn]), 2.0f * acc[mt][nn][r]);
        const u64 key = ((u64)__float_as_uint(d) << 32) |
                        (u32)(n0 + wcb + nn * 16 + (l & 15));
        best = key < best ? key : best;
      }
      bk[mt][r] = best;
    }
  // reduce over the 16 lanes sharing a pixel-row set (lexicographic min)
#pragma unroll
  for (int off = 1; off < 16; off <<= 1) {
#pragma unroll
    for (int mt = 0; mt < 4; ++mt)
#pragma unroll
      for (int r = 0; r < 4; ++r) {
        const u64 o = shfl_xor_u64(bk[mt][r], off);
        if (o < bk[mt][r]) bk[mt][r] = o;
      }
  }

  // cross-wave combine via LDS (reuse zs), then global atomicMin
  u64* part = (u64*)&zs[0][0][0];   // [128][2]
  if ((l & 15) == 0) {
#pragma unroll
    for (int mt = 0; mt < 4; ++mt)
#pragma unroll
      for (int r = 0; r < 4; ++r)
        part[(wpx0 + mt * 16 + (l >> 4) * 4 + r) * 2 + (wid & 1)] = bk[mt][r];
  }
  __syncthreads();
  if (t < 128) {
    const u64 a = part[t * 2], c = part[t * 2 + 1];
    atomicMin(&keys[m0 + t], a < c ? a : c);
  }
}

// ---- outputs: z_q gather + straight-through + loss partials + idx as f32 ----
__global__ __launch_bounds__(256) void vq_outputs_kernel(
    const float* __restrict__ z, const float* __restrict__ emb,
    const unsigned long long* __restrict__ keys, float* __restrict__ out,
    float* __restrict__ out_idx_f, double* __restrict__ loss_accum) {
  const int t  = threadIdx.x;
  const int n0 = blockIdx.x * 64;
  const int m  = t & 63;
  const int c0 = t >> 6;
  const int b  = n0 >> 10;
  const int hw = n0 & 1023;
  const float* zb = z   + (size_t)b * (EMB_DIM * HW) + hw + m;
  float*       ob = out + (size_t)b * (EMB_DIM * HW) + hw + m;
  const int idx = (int)(u32)(keys[n0 + m] & 0xffffffffu);
  const float* er = emb + (size_t)idx * EMB_DIM;
  if (c0 == 0) out_idx_f[n0 + m] = (float)idx;

  double lsum = 0.0;
  for (int c = c0; c < EMB_DIM; c += 4) {
    const float e  = er[c];
    const float zv = zb[(size_t)c * HW];
    const float diff = e - zv;       // fl(z_q - z)
    const float zq   = zv + diff;    // straight-through: fl(z + fl(z_q - z))
    ob[(size_t)c * HW] = zq;
    lsum += (double)diff * (double)diff;
  }

  __shared__ double red[256];
  red[t] = lsum;
  __syncthreads();
  for (int s2 = 128; s2 > 0; s2 >>= 1) {
    if (t < s2) red[t] += red[t + s2];
    __syncthreads();
  }
  if (t == 0) atomicAdd(loss_accum, red[0]);
}

__global__ void vq_finalize_kernel(const double* __restrict__ loss_accum,
                                   float* __restrict__ out_loss) {
  const float L = (float)(*loss_accum / (double)ZQ_ELEMS);
  out_loss[0] = __fadd_rn(L, __fmul_rn(0.25f, L));
}

extern "C" void kernel_launch(void* const* d_in, const int* in_sizes, int n_in,
                              void* d_out, int out_size, void* d_ws, size_t ws_size,
                              hipStream_t stream) {
  const float* z   = (const float*)d_in[0];   // (32, 256, 32, 32) f32
  const float* emb = (const float*)d_in[1];   // (1024, 256) f32

  float* out       = (float*)d_out;           // z_q_out (B,C,H,W)
  float* out_loss  = out + ZQ_ELEMS;          // vq_loss scalar
  float* out_idx_f = out + ZQ_ELEMS + 1;      // encoding_indices as f32

  double* loss_accum = (double*)d_ws;
  float*  tnorm = (float*)((char*)d_ws + WS_TNORM);
  float*  snorm = (float*)((char*)d_ws + WS_SNORM);
  unsigned long long* keys = (unsigned long long*)((char*)d_ws + WS_KEYS);

  vq_prep_kernel<<<132, 256, 0, stream>>>(z, emb, tnorm, snorm, keys, loss_accum);
  vq_main_kernel<<<2048, 256, 0, stream>>>(z, emb, tnorm, snorm, keys);
  vq_outputs_kernel<<<NPIX / 64, 256, 0, stream>>>(z, emb, keys, out, out_idx_f,
                                                   loss_accum);
  vq_finalize_kernel<<<1, 1, 0, stream>>>(loss_accum, out_loss);
}

// Round 5
// 179.918 us; speedup vs baseline: 1.6706x; 1.6706x over previous
//
#include <hip/hip_runtime.h>

#define NUM_EMB 1024
#define EMB_DIM 256
#define NPIX    32768      // 32 * 32 * 32
#define HW      1024       // 32*32 spatial per batch
#define ZQ_ELEMS 8388608   // 32*256*32*32

// ws layout (bytes):
//   [0..8)                  double loss_accum
//   [8..8+4096)             float  tnorm[1024]
//   [8192..8192+131072)     float  snorm[32768]
//   [139264..+262144)       u64    keys[32768]  (argmin: (d_bits<<32)|idx)
//   [401408..+3*524288)     u16    e-planes h/m/l [1024][256]
#define WS_TNORM 8
#define WS_SNORM 8192
#define WS_KEYS  139264
#define WS_EPL   401408
#define EPLANE_ELEMS (NUM_EMB * EMB_DIM)

typedef unsigned long long u64;
typedef unsigned int u32;
typedef unsigned short u16;

typedef __bf16 bf16x8 __attribute__((ext_vector_type(8)));
typedef float f32x4 __attribute__((ext_vector_type(4)));
typedef u16 u16x8 __attribute__((ext_vector_type(8)));

// ---- numpy pairwise_sum replica over 128 squared terms, stride between terms ----
__device__ __forceinline__ float pw128_sq(const float* x, int stride) {
  float r[8];
#pragma unroll
  for (int j = 0; j < 8; ++j) {
    float v = x[(size_t)j * stride];
    r[j] = __fmul_rn(v, v);
  }
  for (int i = 8; i < 128; i += 8) {
#pragma unroll
    for (int j = 0; j < 8; ++j) {
      float v = x[(size_t)(i + j) * stride];
      r[j] = __fadd_rn(r[j], __fmul_rn(v, v));
    }
  }
  float s01 = __fadd_rn(r[0], r[1]);
  float s23 = __fadd_rn(r[2], r[3]);
  float s45 = __fadd_rn(r[4], r[5]);
  float s67 = __fadd_rn(r[6], r[7]);
  return __fadd_rn(__fadd_rn(s01, s23), __fadd_rn(s45, s67));
}

// 3-way bf16 split: x = hf + mf + lf + eps, eps ~ 2^-26 |x|. Sterbenz-exact residuals.
__device__ __forceinline__ void split3(float x, u16& h, u16& m, u16& l) {
  u32 u = __float_as_uint(x);
  u16 hb = (u16)((u + 0x7fffu + ((u >> 16) & 1u)) >> 16);
  float hf = __uint_as_float((u32)hb << 16);
  float r1 = x - hf;                       // exact
  u32 u1 = __float_as_uint(r1);
  u16 mb = (u16)((u1 + 0x7fffu + ((u1 >> 16) & 1u)) >> 16);
  float mf = __uint_as_float((u32)mb << 16);
  float r2 = r1 - mf;                      // exact
  u32 u2 = __float_as_uint(r2);
  u16 lb = (u16)((u2 + 0x7fffu + ((u2 >> 16) & 1u)) >> 16);
  h = hb; m = mb; l = lb;
}

__device__ __forceinline__ u64 shfl_xor_u64(u64 v, int msk) {
  const u32 lo = __shfl_xor((u32)v, msk, 64);
  const u32 hi = __shfl_xor((u32)(v >> 32), msk, 64);
  return ((u64)hi << 32) | lo;
}

// ---- prep: keys=~0, loss=0, snorm (blocks 0..127); tnorm + e-split (blocks 128..131) ----
__global__ __launch_bounds__(256) void vq_prep_kernel(
    const float* __restrict__ z, const float* __restrict__ emb,
    float* __restrict__ tnorm, float* __restrict__ snorm,
    unsigned long long* __restrict__ keys, double* __restrict__ loss_accum,
    u16* __restrict__ eh, u16* __restrict__ em, u16* __restrict__ el) {
  const int gid = blockIdx.x * 256 + threadIdx.x;
  if (gid == 0) *loss_accum = 0.0;
  if (gid < NPIX) {
    keys[gid] = ~0ull;
    const int b = gid >> 10, hw = gid & 1023;
    const float* base = z + (size_t)b * (EMB_DIM * HW) + hw;
    snorm[gid] = __fadd_rn(pw128_sq(base, HW), pw128_sq(base + (size_t)128 * HW, HW));
  } else {
    const int k = gid - NPIX;
    if (k < NUM_EMB) {
      const float* row = emb + (size_t)k * EMB_DIM;
      tnorm[k] = __fadd_rn(pw128_sq(row, 1), pw128_sq(row + 128, 1));
      // split row into 3 bf16 planes, 8 at a time
      for (int c = 0; c < EMB_DIM; c += 8) {
        u16x8 vh, vm, vl;
#pragma unroll
        for (int j = 0; j < 8; ++j) {
          u16 h_, m_, l_;
          split3(row[c + j], h_, m_, l_);
          vh[j] = h_; vm[j] = m_; vl[j] = l_;
        }
        *(u16x8*)(eh + (size_t)k * EMB_DIM + c) = vh;
        *(u16x8*)(em + (size_t)k * EMB_DIM + c) = vm;
        *(u16x8*)(el + (size_t)k * EMB_DIM + c) = vl;
      }
    }
  }
}

// ---- main: 128 px x 128 codes per block, bf16 3-split x 6-product MFMA GEMM ----
// LDS rows are 40 u16 = 80 B (16B-aligned, 20-bank stride self-spreads all
// 16B-chunk accesses across bank groups -> conflict-free b128 reads AND writes).
// logical bid: pt = bid>>3 (256 pixel tiles), nt = bid&7 (8 code tiles)
// XCD swizzle: hw bid h -> logical (h&7)*256 + (h>>3)
__global__ __launch_bounds__(256, 2) void vq_main_kernel(
    const float* __restrict__ z,
    const u16* __restrict__ eh, const u16* __restrict__ em,
    const u16* __restrict__ el,
    const float* __restrict__ tnorm, const float* __restrict__ snorm,
    unsigned long long* __restrict__ keys) {
  __shared__ __align__(16) u16 zs[3][128][40];   // 30720 B
  __shared__ __align__(16) u16 es[3][128][40];   // 30720 B

  const int t   = threadIdx.x;
  const int hb  = blockIdx.x;
  const int bid = (hb & 7) * 256 + (hb >> 3);
  const int pt  = bid >> 3;
  const int ntb = bid & 7;
  const int m0  = pt * 128;
  const int n0  = ntb * 128;
  const int b   = m0 >> 10;
  const int hw0 = m0 & 1023;
  const float* zbase = z + (size_t)b * (EMB_DIM * HW) + hw0;

  const int l    = t & 63;
  const int wid  = t >> 6;
  const int wpx0 = (wid >> 1) * 64;   // wave pixel base within tile
  const int wcb  = (wid & 1) * 64;    // wave code base within tile

  // ---- staging assignment ----
  // z: thread owns pixel pair (p0, p0+1) and k-octet kq (8 k's).
  const int za  = (t & 15) + ((t >> 6) << 4);   // 0..63 pixel-pair index
  const int p0  = za * 2;
  const int kq  = (t >> 4) & 3;                 // k-octet within 32-k tile
  // e: thread owns code (t>>1) and k-half (t&1)*16.
  const int ecode = t >> 1;
  const int ekh   = (t & 1) * 16;
  const u16* eplanes[3] = {eh, em, el};
  const size_t ebase = (size_t)(n0 + ecode) * EMB_DIM + ekh;

  float2 gz[8];
  u16x8  ge[3][2];

  // prologue: load tile kt=0
#pragma unroll
  for (int j = 0; j < 8; ++j)
    gz[j] = *(const float2*)(zbase + (size_t)(kq * 8 + j) * HW + p0);
#pragma unroll
  for (int p = 0; p < 3; ++p) {
    const u16* src = eplanes[p] + ebase;
    ge[p][0] = *(const u16x8*)(src);
    ge[p][1] = *(const u16x8*)(src + 8);
  }

  f32x4 acc[4][4];
#pragma unroll
  for (int i = 0; i < 4; ++i)
#pragma unroll
    for (int j = 0; j < 4; ++j) {
      f32x4 zv = {0.0f, 0.0f, 0.0f, 0.0f};
      acc[i][j] = zv;
    }

  for (int kt = 0; kt < 8; ++kt) {
    // ---- convert + b128 LDS writes ----
#pragma unroll
    for (int r = 0; r < 2; ++r) {
      u16x8 vh, vm, vl;
#pragma unroll
      for (int j = 0; j < 8; ++j) {
        const float x = r ? gz[j].y : gz[j].x;
        u16 h_, m_, l_;
        split3(x, h_, m_, l_);
        vh[j] = h_; vm[j] = m_; vl[j] = l_;
      }
      *(u16x8*)&zs[0][p0 + r][kq * 8] = vh;
      *(u16x8*)&zs[1][p0 + r][kq * 8] = vm;
      *(u16x8*)&zs[2][p0 + r][kq * 8] = vl;
    }
#pragma unroll
    for (int p = 0; p < 3; ++p) {
      *(u16x8*)&es[p][ecode][ekh]     = ge[p][0];
      *(u16x8*)&es[p][ecode][ekh + 8] = ge[p][1];
    }

    // ---- issue next tile's loads (latency hides under MFMA) ----
    if (kt < 7) {
      const int kb = (kt + 1) * 32;
#pragma unroll
      for (int j = 0; j < 8; ++j)
        gz[j] = *(const float2*)(zbase + (size_t)(kb + kq * 8 + j) * HW + p0);
#pragma unroll
      for (int p = 0; p < 3; ++p) {
        const u16* src = eplanes[p] + ebase + kb;
        ge[p][0] = *(const u16x8*)(src);
        ge[p][1] = *(const u16x8*)(src + 8);
      }
    }
    __syncthreads();

    // ---- fragment loads: lane m/n = l&15, k-octet = l>>4 ----
    const int frow = l & 15;
    const int kg8  = (l >> 4) * 8;
    bf16x8 af[3][4], bf[3][4];
#pragma unroll
    for (int mt = 0; mt < 4; ++mt)
#pragma unroll
      for (int p = 0; p < 3; ++p)
        af[p][mt] = *(const bf16x8*)&zs[p][wpx0 + mt * 16 + frow][kg8];
#pragma unroll
    for (int nn = 0; nn < 4; ++nn)
#pragma unroll
      for (int p = 0; p < 3; ++p)
        bf[p][nn] = *(const bf16x8*)&es[p][wcb + nn * 16 + frow][kg8];

    // ---- 6 split-product planes: hh, hm, mh, mm, hl, lh ----
#define MMPAIR(PA, PB)                                                        \
    _Pragma("unroll")                                                         \
    for (int mt = 0; mt < 4; ++mt) {                                          \
      _Pragma("unroll")                                                       \
      for (int nn = 0; nn < 4; ++nn)                                          \
        acc[mt][nn] = __builtin_amdgcn_mfma_f32_16x16x32_bf16(                \
            af[PA][mt], bf[PB][nn], acc[mt][nn], 0, 0, 0);                    \
    }
    MMPAIR(0, 0)
    MMPAIR(0, 1)
    MMPAIR(1, 0)
    MMPAIR(1, 1)
    MMPAIR(0, 2)
    MMPAIR(2, 0)
#undef MMPAIR
    __syncthreads();
  }

  // ---- epilogue: d = fl(fl(s+t) - 2m); argmin via u64 keys ----
  // C layout: col = l&15 (code), row = (l>>4)*4 + reg (pixel)
  float sv[4][4], tv[4];
#pragma unroll
  for (int mt = 0; mt < 4; ++mt)
#pragma unroll
    for (int r = 0; r < 4; ++r)
      sv[mt][r] = snorm[m0 + wpx0 + mt * 16 + (l >> 4) * 4 + r];
#pragma unroll
  for (int nn = 0; nn < 4; ++nn)
    tv[nn] = tnorm[n0 + wcb + nn * 16 + (l & 15)];

  u64 bk[4][4];
#pragma unroll
  for (int mt = 0; mt < 4; ++mt)
#pragma unroll
    for (int r = 0; r < 4; ++r) {
      u64 best = ~0ull;
#pragma unroll
      for (int nn = 0; nn < 4; ++nn) {
        const float d =
            __fsub_rn(__fadd_rn(sv[mt][r], tv[nn]), 2.0f * acc[mt][nn][r]);
        const u64 key = ((u64)__float_as_uint(d) << 32) |
                        (u32)(n0 + wcb + nn * 16 + (l & 15));
        best = key < best ? key : best;
      }
      bk[mt][r] = best;
    }
  // reduce over the 16 lanes sharing a pixel-row set (lexicographic min)
#pragma unroll
  for (int off = 1; off < 16; off <<= 1) {
#pragma unroll
    for (int mt = 0; mt < 4; ++mt)
#pragma unroll
      for (int r = 0; r < 4; ++r) {
        const u64 o = shfl_xor_u64(bk[mt][r], off);
        if (o < bk[mt][r]) bk[mt][r] = o;
      }
  }

  // cross-wave combine via LDS (reuse zs), then global atomicMin
  u64* part = (u64*)&zs[0][0][0];   // [128][2]
  if ((l & 15) == 0) {
#pragma unroll
    for (int mt = 0; mt < 4; ++mt)
#pragma unroll
      for (int r = 0; r < 4; ++r)
        part[(wpx0 + mt * 16 + (l >> 4) * 4 + r) * 2 + (wid & 1)] = bk[mt][r];
  }
  __syncthreads();
  if (t < 128) {
    const u64 a = part[t * 2], c = part[t * 2 + 1];
    atomicMin(&keys[m0 + t], a < c ? a : c);
  }
}

// ---- outputs: z_q gather + straight-through + loss partials + idx as f32 ----
__global__ __launch_bounds__(256) void vq_outputs_kernel(
    const float* __restrict__ z, const float* __restrict__ emb,
    const unsigned long long* __restrict__ keys, float* __restrict__ out,
    float* __restrict__ out_idx_f, double* __restrict__ loss_accum) {
  const int t  = threadIdx.x;
  const int n0 = blockIdx.x * 64;
  const int m  = t & 63;
  const int c0 = t >> 6;
  const int b  = n0 >> 10;
  const int hw = n0 & 1023;
  const float* zb = z   + (size_t)b * (EMB_DIM * HW) + hw + m;
  float*       ob = out + (size_t)b * (EMB_DIM * HW) + hw + m;
  const int idx = (int)(u32)(keys[n0 + m] & 0xffffffffu);
  const float* er = emb + (size_t)idx * EMB_DIM;
  if (c0 == 0) out_idx_f[n0 + m] = (float)idx;

  double lsum = 0.0;
  for (int c = c0; c < EMB_DIM; c += 4) {
    const float e  = er[c];
    const float zv = zb[(size_t)c * HW];
    const float diff = e - zv;       // fl(z_q - z)
    const float zq   = zv + diff;    // straight-through: fl(z + fl(z_q - z))
    ob[(size_t)c * HW] = zq;
    lsum += (double)diff * (double)diff;
  }

  __shared__ double red[256];
  red[t] = lsum;
  __syncthreads();
  for (int s2 = 128; s2 > 0; s2 >>= 1) {
    if (t < s2) red[t] += red[t + s2];
    __syncthreads();
  }
  if (t == 0) atomicAdd(loss_accum, red[0]);
}

__global__ void vq_finalize_kernel(const double* __restrict__ loss_accum,
                                   float* __restrict__ out_loss) {
  const float L = (float)(*loss_accum / (double)ZQ_ELEMS);
  out_loss[0] = __fadd_rn(L, __fmul_rn(0.25f, L));
}

extern "C" void kernel_launch(void* const* d_in, const int* in_sizes, int n_in,
                              void* d_out, int out_size, void* d_ws, size_t ws_size,
                              hipStream_t stream) {
  const float* z   = (const float*)d_in[0];   // (32, 256, 32, 32) f32
  const float* emb = (const float*)d_in[1];   // (1024, 256) f32

  float* out       = (float*)d_out;           // z_q_out (B,C,H,W)
  float* out_loss  = out + ZQ_ELEMS;          // vq_loss scalar
  float* out_idx_f = out + ZQ_ELEMS + 1;      // encoding_indices as f32

  double* loss_accum = (double*)d_ws;
  float*  tnorm = (float*)((char*)d_ws + WS_TNORM);
  float*  snorm = (float*)((char*)d_ws + WS_SNORM);
  unsigned long long* keys = (unsigned long long*)((char*)d_ws + WS_KEYS);
  u16* eh = (u16*)((char*)d_ws + WS_EPL);
  u16* em = eh + EPLANE_ELEMS;
  u16* el = em + EPLANE_ELEMS;

  vq_prep_kernel<<<132, 256, 0, stream>>>(z, emb, tnorm, snorm, keys, loss_accum,
                                          eh, em, el);
  vq_main_kernel<<<2048, 256, 0, stream>>>(z, eh, em, el, tnorm, snorm, keys);
  vq_outputs_kernel<<<NPIX / 64, 256, 0, stream>>>(z, emb, keys, out, out_idx_f,
                                                   loss_accum);
  vq_finalize_kernel<<<1, 1, 0, stream>>>(loss_accum, out_loss);
}